// Round 5
// baseline (1869.685 us; speedup 1.0000x reference)
//
#include <hip/hip_runtime.h>
#include <hip/hip_bf16.h>

typedef unsigned short u16;
typedef __bf16 bf16x8 __attribute__((ext_vector_type(8)));
typedef float f32x4 __attribute__((ext_vector_type(4)));

__device__ __forceinline__ float bf2f(u16 u) {
    unsigned v = ((unsigned)u) << 16;
    return __builtin_bit_cast(float, v);
}
__device__ __forceinline__ u16 f2bf(float f) {
    unsigned x = __builtin_bit_cast(unsigned, f);
    unsigned r = x + (0x7fffu + ((x >> 16) & 1u));   // RNE
    return (u16)(r >> 16);
}

// ---------------- LayerNorm: one wave per pixel (fp32 in, bf16 out) ----------
template<int C>
__global__ __launch_bounds__(256) void ln_kernel(const float* __restrict__ xf,
    const float* __restrict__ g, const float* __restrict__ b,
    u16* __restrict__ out, int npix)
{
    int wid = threadIdx.x >> 6, lane = threadIdx.x & 63;
    int pix = blockIdx.x * 4 + wid;
    if (pix >= npix) return;
    constexpr int J = C / 64;
    float v[J];
    float s = 0.f, s2 = 0.f;
#pragma unroll
    for (int j = 0; j < J; j++) {
        int c = lane + j * 64;
        float t = xf[(size_t)pix * C + c];
        v[j] = t; s += t; s2 += t * t;
    }
#pragma unroll
    for (int off = 32; off; off >>= 1) {
        s  += __shfl_xor(s,  off, 64);
        s2 += __shfl_xor(s2, off, 64);
    }
    float mean = s / C;
    float var = fmaxf(s2 / C - mean * mean, 0.f);
    float rs = rsqrtf(var + 1e-6f);
#pragma unroll
    for (int j = 0; j < J; j++) {
        int c = lane + j * 64;
        float o = (v[j] - mean) * rs * g[c] + b[c];
        out[(size_t)pix * C + c] = f2bf(o);
    }
}

// ---------------- Generic bf16 MFMA GEMM, 64x64 tile, BK=32 ----------------
// A: bf16 internal buffer. B: fp32 weights, row-major K x ldb (caller
// pre-offsets Bm/bias to the column window), converted bf16 at staging.
enum { GA_NONE = 0, GA_WIN = 1 };
enum { EPI_STORE = 0, EPI_GELU = 1, EPI_PROJ = 2, EPI_OUT = 3 };

template<int GATHER, int EPI>
__global__ __launch_bounds__(256) void gemm_bf16(
    const u16* __restrict__ A, const float* __restrict__ Bm, int ldb,
    const float* __restrict__ bias, u16* __restrict__ Cb,
    float* __restrict__ Yf, float* __restrict__ Of,
    int M, int N, int K)
{
    __shared__ __align__(16) u16 As[64][40];   // [m][k], pad 32->40
    __shared__ __align__(16) u16 Bs[64][40];   // [n][k]  (B transposed)
    __shared__ int rowsrc[64];

    const int tid = threadIdx.x;
    const int bm = blockIdx.x, bn = blockIdx.y;

    if (tid < 64) {
        int gm = bm * 64 + tid;
        int src = -1;
        if (gm < M) {
            if (GATHER == GA_WIN) {
                int w = gm / 196, t = gm % 196;
                int b = w / 25, wh = (w / 5) % 5, ww = w % 5;
                int ty = t / 14, tx = t % 14;
                int gh = wh * 14 + ty, gw = ww * 14 + tx;
                if (gh < 64 && gw < 64) src = (b * 64 + gh) * 64 + gw;
            } else {
                src = gm;
            }
        }
        rowsrc[tid] = src;
    }
    __syncthreads();

    const int wid = tid >> 6, lane = tid & 63;
    const int wm = wid >> 1, wn = wid & 1;
    const int frow = lane & 15, quad = lane >> 4, kb = quad * 8;

    f32x4 acc[2][2] = {};

    const int ar = tid >> 2, akc = (tid & 3) * 8;  // A staging: row, k-chunk
    const int bnn = tid & 63, bk0 = tid >> 6;      // B staging: n, k-start

    for (int k0 = 0; k0 < K; k0 += 32) {
        {   // stage A (64x32), 16B per thread
            int src = rowsrc[ar];
            uint4 val = make_uint4(0u, 0u, 0u, 0u);
            if (src >= 0) val = *(const uint4*)(A + (size_t)src * K + k0 + akc);
            *(uint4*)&As[ar][akc] = val;
        }
        {   // stage B (32 x 64 slice), fp32 -> bf16, transposed into Bs[n][k]
            int gn = bn * 64 + bnn;
#pragma unroll
            for (int kk = bk0; kk < 32; kk += 4)
                Bs[bnn][kk] = f2bf(Bm[(size_t)(k0 + kk) * ldb + gn]);
        }
        __syncthreads();
#pragma unroll
        for (int mi = 0; mi < 2; mi++) {
            bf16x8 af = *(const bf16x8*)&As[wm * 32 + mi * 16 + frow][kb];
#pragma unroll
            for (int ni = 0; ni < 2; ni++) {
                bf16x8 bfv = *(const bf16x8*)&Bs[wn * 32 + ni * 16 + frow][kb];
                acc[mi][ni] = __builtin_amdgcn_mfma_f32_16x16x32_bf16(af, bfv, acc[mi][ni], 0, 0, 0);
            }
        }
        __syncthreads();
    }

    // epilogue: D lane layout col = lane&15, row = quad*4 + i
#pragma unroll
    for (int mi = 0; mi < 2; mi++)
#pragma unroll
    for (int ni = 0; ni < 2; ni++)
#pragma unroll
    for (int i = 0; i < 4; i++) {
        int gm = bm * 64 + wm * 32 + mi * 16 + quad * 4 + i;
        int gn = bn * 64 + wn * 32 + ni * 16 + frow;
        if (gm >= M) continue;
        float val = acc[mi][ni][i] + bias[gn];
        if (EPI == EPI_STORE) {
            Cb[(size_t)gm * N + gn] = f2bf(val);
        } else if (EPI == EPI_GELU) {
            float ge = 0.5f * val * (1.0f + erff(val * 0.70710678118654752f));
            Cb[(size_t)gm * N + gn] = f2bf(ge);
        } else if (EPI == EPI_PROJ) {
            int w = gm / 49, q = gm % 49;
            int b = w / 25, wh = (w / 5) % 5, ww = w % 5;
            int qy = q / 7, qx = q % 7;
            int oy = wh * 7 + qy, ox = ww * 7 + qx;
            if (oy < 32 && ox < 32) {
                size_t pix = (size_t)((b * 32 + oy) * 32 + ox);
                Yf[pix * 896 + gn] += val;   // y = shortcut + xo
            }
        } else { // EPI_OUT: final output is FP32 (reference output dtype)
            Of[(size_t)gm * 896 + gn] = val + Yf[(size_t)gm * 896 + gn];
        }
    }
}

// ---------------- 2x2 maxpool of skip GEMM output -> y (fp32) ----------------
__global__ __launch_bounds__(256) void maxpool_skip(const u16* __restrict__ s,
                                                    float* __restrict__ y, int total)
{
    int id = blockIdx.x * 256 + threadIdx.x;
    if (id >= total) return;
    int c = id % 896, p = id / 896;
    int b = p >> 10, rem = p & 1023, oy = rem >> 5, ox = rem & 31;
    size_t base = ((size_t)((b * 64 + 2 * oy) * 64 + 2 * ox)) * 896 + c;
    float m = bf2f(s[base]);
    m = fmaxf(m, bf2f(s[base + 896]));
    m = fmaxf(m, bf2f(s[base + 64 * 896]));
    m = fmaxf(m, bf2f(s[base + 64 * 896 + 896]));
    y[id] = m;
}

// ---------------- 2x2 maxpool of qfull (39200x896) -> qp (9800x896) ----------
__global__ __launch_bounds__(256) void qpool(const u16* __restrict__ qf,
                                             u16* __restrict__ qp, int total)
{
    int id = blockIdx.x * 256 + threadIdx.x;
    if (id >= total) return;
    int c = id % 896; int rq = id / 896;
    int q = rq % 49, w = rq / 49;
    int qy = q / 7, qx = q % 7;
    int t0 = (2 * qy) * 14 + 2 * qx;
    size_t base = (size_t)(w * 196 + t0) * 896 + c;
    float m = bf2f(qf[base]);
    m = fmaxf(m, bf2f(qf[base + 896]));
    m = fmaxf(m, bf2f(qf[base + 14 * 896]));
    m = fmaxf(m, bf2f(qf[base + 15 * 896]));
    qp[id] = f2bf(m);
}

// ---------------- attention: one block per (window, head) ----------------
__global__ __launch_bounds__(256) void attn_kernel(const u16* __restrict__ qp,
    const u16* __restrict__ kb, const u16* __restrict__ vb, u16* __restrict__ ao)
{
    __shared__ float S[49][196];
    __shared__ u16 kv[196][56];
    const float SCALE = 0.13363062095621219f;  // 56^-0.5
    int w = blockIdx.x >> 4, h = blockIdx.x & 15;
    int tid = threadIdx.x;

    for (int idx = tid; idx < 196 * 56; idx += 256) {   // load k head-slice
        int j = idx / 56, d = idx % 56;
        kv[j][d] = kb[(size_t)(w * 196 + j) * 896 + h * 56 + d];
    }
    __syncthreads();

    for (int p = tid; p < 49 * 196; p += 256) {          // S = scale * q @ k^T
        int i = p / 196, j = p % 196;
        const u16* qrow = qp + (size_t)(w * 49 + i) * 896 + h * 56;
        float s = 0.f;
#pragma unroll
        for (int d = 0; d < 56; d++) s += bf2f(qrow[d]) * bf2f(kv[j][d]);
        S[i][j] = s * SCALE;
    }
    __syncthreads();

    if (tid < 49) {                                      // softmax rows
        float mx = -1e30f;
        for (int j = 0; j < 196; j++) mx = fmaxf(mx, S[tid][j]);
        float sum = 0.f;
        for (int j = 0; j < 196; j++) { float e = __expf(S[tid][j] - mx); S[tid][j] = e; sum += e; }
        float inv = 1.0f / sum;
        for (int j = 0; j < 196; j++) S[tid][j] *= inv;
    }
    __syncthreads();

    for (int idx = tid; idx < 196 * 56; idx += 256) {    // load v head-slice
        int j = idx / 56, d = idx % 56;
        kv[j][d] = vb[(size_t)(w * 196 + j) * 896 + h * 56 + d];
    }
    __syncthreads();

    for (int p = tid; p < 49 * 56; p += 256) {           // out = S @ v
        int i = p / 56, d = p % 56;
        float s = 0.f;
        for (int j = 0; j < 196; j++) s += S[i][j] * bf2f(kv[j][d]);
        ao[(size_t)(w * 49 + i) * 896 + h * 56 + d] = f2bf(s);
    }
}

extern "C" void kernel_launch(void* const* d_in, const int* in_sizes, int n_in,
                              void* d_out, int out_size, void* d_ws, size_t ws_size,
                              hipStream_t stream)
{
    // Inputs: fp32 (R2 bf16-read gave NaN -> buffers hold fp32 bit patterns).
    // Output: fp32 (reference output dtype float32; harness reads np.float32.
    //   R3/R4 wrote bf16 here -> half buffer zero + misaligned halves ->
    //   core-independent absmax 3.898 > max|ref|).
    const float* x    = (const float*)d_in[0];
    const float* ln1g = (const float*)d_in[1];
    const float* ln1b = (const float*)d_in[2];
    const float* qkvw = (const float*)d_in[3];
    const float* qkvb = (const float*)d_in[4];
    const float* pw   = (const float*)d_in[5];
    const float* pb   = (const float*)d_in[6];
    const float* sw   = (const float*)d_in[7];
    const float* sb   = (const float*)d_in[8];
    const float* ln2g = (const float*)d_in[9];
    const float* ln2b = (const float*)d_in[10];
    const float* m1w  = (const float*)d_in[11];
    const float* m1b  = (const float*)d_in[12];
    const float* m2w  = (const float*)d_in[13];
    const float* m2b  = (const float*)d_in[14];

    char* ws = (char*)d_ws;
    // ws layout, lifetime-aliased. Peak 234,336,256 B.
    u16*   slot1 = (u16*)(ws + 0);            // 70,246,400 B
    u16*   vbuf  = (u16*)(ws + 70246400);     // 70,246,400 B
    u16*   hn    = (u16*)(ws + 140492800);    // 29,360,128 B
    float* Yf    = (float*)(ws + 169852928);  // 29,360,128 B (8192*896 fp32)
    u16*   qp    = (u16*)(ws + 199213056);    // 17,561,600 B
    u16*   ao    = (u16*)(ws + 216774656);    // 17,561,600 B
    u16*   sskip = slot1;
    u16*   qfull = slot1;
    u16*   kbuf  = slot1;
    u16*   m1    = slot1;
    u16*   hn2   = hn;
    float* outf  = (float*)d_out;

    // 1. hn = LN1(x)
    ln_kernel<448><<<8192, 256, 0, stream>>>(x, ln1g, ln1b, hn, 32768);
    // 2. sskip = hn @ skip_w + skip_b
    gemm_bf16<GA_NONE, EPI_STORE><<<dim3(512, 14), 256, 0, stream>>>(
        hn, sw, 896, sb, sskip, nullptr, nullptr, 32768, 896, 448);
    // 3. y = maxpool2x2(sskip)
    maxpool_skip<<<28672, 256, 0, stream>>>(sskip, Yf, 8192 * 896);
    // 4. qfull = window_gather(hn) @ Wq + bq
    gemm_bf16<GA_WIN, EPI_STORE><<<dim3(613, 14), 256, 0, stream>>>(
        hn, qkvw + 0, 2688, qkvb + 0, qfull, nullptr, nullptr, 39200, 896, 448);
    // 5. qp = maxpool2x2(qfull)
    qpool<<<34300, 256, 0, stream>>>(qfull, qp, 200 * 49 * 896);
    // 6. kbuf = window_gather(hn) @ Wk + bk
    gemm_bf16<GA_WIN, EPI_STORE><<<dim3(613, 14), 256, 0, stream>>>(
        hn, qkvw + 896, 2688, qkvb + 896, kbuf, nullptr, nullptr, 39200, 896, 448);
    // 7. vbuf = window_gather(hn) @ Wv + bv
    gemm_bf16<GA_WIN, EPI_STORE><<<dim3(613, 14), 256, 0, stream>>>(
        hn, qkvw + 1792, 2688, qkvb + 1792, vbuf, nullptr, nullptr, 39200, 896, 448);
    // 8. attention
    attn_kernel<<<3200, 256, 0, stream>>>(qp, kbuf, vbuf, ao);
    // 9. y += window_scatter(ao @ proj_w + proj_b)
    gemm_bf16<GA_NONE, EPI_PROJ><<<dim3(154, 14), 256, 0, stream>>>(
        ao, pw, 896, pb, nullptr, Yf, nullptr, 9800, 896, 896);
    // 10. hn2 = LN2(y)
    ln_kernel<896><<<2048, 256, 0, stream>>>(Yf, ln2g, ln2b, hn2, 8192);
    // 11. m1 = gelu(hn2 @ mlp1_w + mlp1_b)
    gemm_bf16<GA_NONE, EPI_GELU><<<dim3(128, 56), 256, 0, stream>>>(
        hn2, m1w, 3584, m1b, m1, nullptr, nullptr, 8192, 3584, 896);
    // 12. out = y + m1 @ mlp2_w + mlp2_b   (fp32 store)
    gemm_bf16<GA_NONE, EPI_OUT><<<dim3(128, 14), 256, 0, stream>>>(
        m1, m2w, 896, m2b, nullptr, Yf, outf, 8192, 896, 3584);
}

// Round 6
// 1523.724 us; speedup vs baseline: 1.2270x; 1.2270x over previous
//
#include <hip/hip_runtime.h>
#include <hip/hip_bf16.h>

typedef unsigned short u16;
typedef __bf16 bf16x8 __attribute__((ext_vector_type(8)));
typedef float f32x4 __attribute__((ext_vector_type(4)));

__device__ __forceinline__ float bf2f(u16 u) {
    unsigned v = ((unsigned)u) << 16;
    return __builtin_bit_cast(float, v);
}
__device__ __forceinline__ u16 f2bf(float f) {
    unsigned x = __builtin_bit_cast(unsigned, f);
    unsigned r = x + (0x7fffu + ((x >> 16) & 1u));   // RNE
    return (u16)(r >> 16);
}

// ---------------- LayerNorm: one wave per pixel (fp32 in, bf16 out) ----------
template<int C>
__global__ __launch_bounds__(256) void ln_kernel(const float* __restrict__ xf,
    const float* __restrict__ g, const float* __restrict__ b,
    u16* __restrict__ out, int npix)
{
    int wid = threadIdx.x >> 6, lane = threadIdx.x & 63;
    int pix = blockIdx.x * 4 + wid;
    if (pix >= npix) return;
    constexpr int J = C / 64;
    float v[J];
    float s = 0.f, s2 = 0.f;
#pragma unroll
    for (int j = 0; j < J; j++) {
        int c = lane + j * 64;
        float t = xf[(size_t)pix * C + c];
        v[j] = t; s += t; s2 += t * t;
    }
#pragma unroll
    for (int off = 32; off; off >>= 1) {
        s  += __shfl_xor(s,  off, 64);
        s2 += __shfl_xor(s2, off, 64);
    }
    float mean = s / C;
    float var = fmaxf(s2 / C - mean * mean, 0.f);
    float rs = rsqrtf(var + 1e-6f);
#pragma unroll
    for (int j = 0; j < J; j++) {
        int c = lane + j * 64;
        float o = (v[j] - mean) * rs * g[c] + b[c];
        out[(size_t)pix * C + c] = f2bf(o);
    }
}

// ---------------- Generic bf16 MFMA GEMM, 64x64 tile, BK=32 ----------------
enum { GA_NONE = 0, GA_WIN = 1 };
enum { EPI_STORE = 0, EPI_GELU = 1, EPI_PROJ = 2, EPI_OUT = 3 };

template<int GATHER, int EPI>
__global__ __launch_bounds__(256) void gemm_bf16(
    const u16* __restrict__ A, const float* __restrict__ Bm, int ldb,
    const float* __restrict__ bias, u16* __restrict__ Cb,
    float* __restrict__ Yf, float* __restrict__ Of,
    int M, int N, int K)
{
    __shared__ __align__(16) u16 As[64][40];   // [m][k], pad 32->40
    __shared__ __align__(16) u16 Bs[64][40];   // [n][k]  (B transposed)
    __shared__ int rowsrc[64];

    const int tid = threadIdx.x;
    const int bm = blockIdx.x, bn = blockIdx.y;

    if (tid < 64) {
        int gm = bm * 64 + tid;
        int src = -1;
        if (gm < M) {
            if (GATHER == GA_WIN) {
                int w = gm / 196, t = gm % 196;
                int b = w / 25, wh = (w / 5) % 5, ww = w % 5;
                int ty = t / 14, tx = t % 14;
                int gh = wh * 14 + ty, gw = ww * 14 + tx;
                if (gh < 64 && gw < 64) src = (b * 64 + gh) * 64 + gw;
            } else {
                src = gm;
            }
        }
        rowsrc[tid] = src;
    }
    __syncthreads();

    const int wid = tid >> 6, lane = tid & 63;
    const int wm = wid >> 1, wn = wid & 1;
    const int frow = lane & 15, quad = lane >> 4, kb = quad * 8;

    f32x4 acc[2][2] = {};

    const int ar = tid >> 2, akc = (tid & 3) * 8;  // A staging: row, k-chunk
    const int bnn = tid & 63, bk0 = tid >> 6;      // B staging: n, k-start

    for (int k0 = 0; k0 < K; k0 += 32) {
        {   // stage A (64x32), 16B per thread
            int src = rowsrc[ar];
            uint4 val = make_uint4(0u, 0u, 0u, 0u);
            if (src >= 0) val = *(const uint4*)(A + (size_t)src * K + k0 + akc);
            *(uint4*)&As[ar][akc] = val;
        }
        {   // stage B (32 x 64 slice), fp32 -> bf16, transposed into Bs[n][k]
            int gn = bn * 64 + bnn;
#pragma unroll
            for (int kk = bk0; kk < 32; kk += 4)
                Bs[bnn][kk] = f2bf(Bm[(size_t)(k0 + kk) * ldb + gn]);
        }
        __syncthreads();
#pragma unroll
        for (int mi = 0; mi < 2; mi++) {
            bf16x8 af = *(const bf16x8*)&As[wm * 32 + mi * 16 + frow][kb];
#pragma unroll
            for (int ni = 0; ni < 2; ni++) {
                bf16x8 bfv = *(const bf16x8*)&Bs[wn * 32 + ni * 16 + frow][kb];
                acc[mi][ni] = __builtin_amdgcn_mfma_f32_16x16x32_bf16(af, bfv, acc[mi][ni], 0, 0, 0);
            }
        }
        __syncthreads();
    }

    // epilogue: D lane layout col = lane&15, row = quad*4 + i
#pragma unroll
    for (int mi = 0; mi < 2; mi++)
#pragma unroll
    for (int ni = 0; ni < 2; ni++)
#pragma unroll
    for (int i = 0; i < 4; i++) {
        int gm = bm * 64 + wm * 32 + mi * 16 + quad * 4 + i;
        int gn = bn * 64 + wn * 32 + ni * 16 + frow;
        if (gm >= M) continue;
        float val = acc[mi][ni][i] + bias[gn];
        if (EPI == EPI_STORE) {
            Cb[(size_t)gm * N + gn] = f2bf(val);
        } else if (EPI == EPI_GELU) {
            float ge = 0.5f * val * (1.0f + erff(val * 0.70710678118654752f));
            Cb[(size_t)gm * N + gn] = f2bf(ge);
        } else if (EPI == EPI_PROJ) {
            int w = gm / 49, q = gm % 49;
            int b = w / 25, wh = (w / 5) % 5, ww = w % 5;
            int qy = q / 7, qx = q % 7;
            int oy = wh * 7 + qy, ox = ww * 7 + qx;
            if (oy < 32 && ox < 32) {
                size_t pix = (size_t)((b * 32 + oy) * 32 + ox);
                Yf[pix * 896 + gn] += val;   // y = shortcut + xo
            }
        } else { // EPI_OUT: final output is FP32
            Of[(size_t)gm * 896 + gn] = val + Yf[(size_t)gm * 896 + gn];
        }
    }
}

// ---------------- 2x2 maxpool of skip GEMM output -> y (fp32) ----------------
__global__ __launch_bounds__(256) void maxpool_skip(const u16* __restrict__ s,
                                                    float* __restrict__ y, int total)
{
    int id = blockIdx.x * 256 + threadIdx.x;
    if (id >= total) return;
    int c = id % 896, p = id / 896;
    int b = p >> 10, rem = p & 1023, oy = rem >> 5, ox = rem & 31;
    size_t base = ((size_t)((b * 64 + 2 * oy) * 64 + 2 * ox)) * 896 + c;
    float m = bf2f(s[base]);
    m = fmaxf(m, bf2f(s[base + 896]));
    m = fmaxf(m, bf2f(s[base + 64 * 896]));
    m = fmaxf(m, bf2f(s[base + 64 * 896 + 896]));
    y[id] = m;
}

// ---------------- 2x2 maxpool of qfull (39200x896) -> qp (9800x896) ----------
__global__ __launch_bounds__(256) void qpool(const u16* __restrict__ qf,
                                             u16* __restrict__ qp, int total)
{
    int id = blockIdx.x * 256 + threadIdx.x;
    if (id >= total) return;
    int c = id % 896; int rq = id / 896;
    int q = rq % 49, w = rq / 49;
    int qy = q / 7, qx = q % 7;
    int t0 = (2 * qy) * 14 + 2 * qx;
    size_t base = (size_t)(w * 196 + t0) * 896 + c;
    float m = bf2f(qf[base]);
    m = fmaxf(m, bf2f(qf[base + 896]));
    m = fmaxf(m, bf2f(qf[base + 14 * 896]));
    m = fmaxf(m, bf2f(qf[base + 15 * 896]));
    qp[id] = f2bf(m);
}

// ---------------- MFMA attention: one block per (window, head) ---------------
// QK^T (49x196x56) and PV (49x56x196) on matrix cores; S lives in registers
// (13 f32x4/lane), softmax in-register via 16-lane xor shuffles.
// Padding: M 49->64 (clamped q rows, discarded at store), N 196->208 (masked
// in softmax, P=0), K 56->64 (zeros), PV-K 196->224 (P=0 and Vs pad zeroed).
__global__ __launch_bounds__(256) void attn_mfma(const u16* __restrict__ qp,
    const u16* __restrict__ kbuf, const u16* __restrict__ vbuf,
    u16* __restrict__ ao)
{
    __shared__ __align__(16) u16 Ps[64][232];   // P bf16 [m][j], 29,696 B
    __shared__ __align__(16) u16 KV[208 * 72];  // k [n][72] -> v [d][232]; 29,952 B

    const float SCALE = 0.13363062095621219f;   // 56^-0.5
    const int w = blockIdx.x >> 4, h = blockIdx.x & 15;
    const int tid = threadIdx.x;
    const int wid = tid >> 6, lane = tid & 63;
    const int n16 = lane & 15, quad = lane >> 4;

    // ---- phase 0: zero Ps, stage k -> KV[n][kk], load q A-frags ----
    for (int idx = tid; idx < 64 * 232 / 8; idx += 256)       // memset Ps (16B)
        *(uint4*)&Ps[0][idx * 8] = make_uint4(0u, 0u, 0u, 0u);
    for (int idx = tid; idx < 208 * 9; idx += 256) {          // k: 208 rows x 9 chunks
        int n = idx / 9, kc = (idx % 9) * 8;
        uint4 val = make_uint4(0u, 0u, 0u, 0u);
        if (n < 196 && kc < 56)
            val = *(const uint4*)(kbuf + (size_t)(w * 196 + n) * 896 + h * 56 + kc);
        *(uint4*)&KV[n * 72 + kc] = val;
    }
    bf16x8 qf[2];
    {
        int m = 16 * wid + n16;
        int row = w * 49 + (m < 49 ? m : 48);   // clamp: rows >=49 discarded later
        const u16* src = qp + (size_t)row * 896 + h * 56;
#pragma unroll
        for (int ks = 0; ks < 2; ks++) {
            int kk = ks * 32 + quad * 8;
            uint4 v = make_uint4(0u, 0u, 0u, 0u);
            if (kk < 56) v = *(const uint4*)(src + kk);
            qf[ks] = __builtin_bit_cast(bf16x8, v);
        }
    }
    __syncthreads();

    // ---- phase 1: S = q k^T (each wave owns m-tile=wid, all 13 n-tiles) ----
    f32x4 S[13] = {};
#pragma unroll
    for (int nt = 0; nt < 13; nt++) {
#pragma unroll
        for (int ks = 0; ks < 2; ks++) {
            bf16x8 bf = *(const bf16x8*)&KV[(nt * 16 + n16) * 72 + ks * 32 + quad * 8];
            S[nt] = __builtin_amdgcn_mfma_f32_16x16x32_bf16(qf[ks], bf, S[nt], 0, 0, 0);
        }
    }
    // in-register softmax. Lane holds rows 4*quad+i (i=0..3) of m-tile, col 16*nt+n16.
#pragma unroll
    for (int i = 0; i < 4; i++) {
        float mx = -3.0e38f;
#pragma unroll
        for (int nt = 0; nt < 13; nt++) {
            float v = S[nt][i] * SCALE;
            S[nt][i] = v;
            if (nt < 12 || n16 < 4) mx = fmaxf(mx, v);   // mask cols >=196
        }
        mx = fmaxf(mx, __shfl_xor(mx, 1, 64));
        mx = fmaxf(mx, __shfl_xor(mx, 2, 64));
        mx = fmaxf(mx, __shfl_xor(mx, 4, 64));
        mx = fmaxf(mx, __shfl_xor(mx, 8, 64));
        float sm = 0.f;
#pragma unroll
        for (int nt = 0; nt < 13; nt++) {
            float e = (nt < 12 || n16 < 4) ? __expf(S[nt][i] - mx) : 0.f;
            S[nt][i] = e;
            sm += e;
        }
        sm += __shfl_xor(sm, 1, 64);
        sm += __shfl_xor(sm, 2, 64);
        sm += __shfl_xor(sm, 4, 64);
        sm += __shfl_xor(sm, 8, 64);
        float inv = 1.f / sm;
#pragma unroll
        for (int nt = 0; nt < 13; nt++) S[nt][i] *= inv;
    }
    __syncthreads();   // all waves done reading k from KV

    // ---- phase 2: write P -> Ps (bf16), stage v transposed -> Vs[d][j] ----
#pragma unroll
    for (int nt = 0; nt < 13; nt++)
#pragma unroll
        for (int i = 0; i < 4; i++)
            Ps[16 * wid + 4 * quad + i][16 * nt + n16] = f2bf(S[nt][i]);

    u16 (*Vs)[232] = reinterpret_cast<u16(*)[232]>(KV);
    for (int idx = tid; idx < 196 * 56; idx += 256) {   // fill (coalesced in d)
        int j = idx / 56, d = idx % 56;
        Vs[d][j] = vbuf[(size_t)(w * 196 + j) * 896 + h * 56 + d];
    }
    for (int idx = tid; idx < 64 * 14; idx += 256) {    // zero pad j in [196,224)
        int d = idx / 14, c = idx % 14;
        *(unsigned*)&Vs[d][196 + 2 * c] = 0u;
    }
    __syncthreads();

    // ---- phase 3: O = P @ v  (m-tile=wid, 4 n-tiles of d, K=224) ----
    f32x4 O[4] = {};
#pragma unroll
    for (int ks = 0; ks < 7; ks++) {
        bf16x8 a = *(const bf16x8*)&Ps[16 * wid + n16][ks * 32 + quad * 8];
#pragma unroll
        for (int nt = 0; nt < 4; nt++) {
            bf16x8 b = *(const bf16x8*)&Vs[16 * nt + n16][ks * 32 + quad * 8];
            O[nt] = __builtin_amdgcn_mfma_f32_16x16x32_bf16(a, b, O[nt], 0, 0, 0);
        }
    }
#pragma unroll
    for (int nt = 0; nt < 4; nt++)
#pragma unroll
        for (int i = 0; i < 4; i++) {
            int m = 16 * wid + 4 * quad + i;
            int d = 16 * nt + n16;
            if (m < 49 && d < 56)
                ao[(size_t)(w * 49 + m) * 896 + h * 56 + d] = f2bf(O[nt][i]);
        }
}

extern "C" void kernel_launch(void* const* d_in, const int* in_sizes, int n_in,
                              void* d_out, int out_size, void* d_ws, size_t ws_size,
                              hipStream_t stream)
{
    // Inputs fp32; output fp32 (verified R5).
    const float* x    = (const float*)d_in[0];
    const float* ln1g = (const float*)d_in[1];
    const float* ln1b = (const float*)d_in[2];
    const float* qkvw = (const float*)d_in[3];
    const float* qkvb = (const float*)d_in[4];
    const float* pw   = (const float*)d_in[5];
    const float* pb   = (const float*)d_in[6];
    const float* sw   = (const float*)d_in[7];
    const float* sb   = (const float*)d_in[8];
    const float* ln2g = (const float*)d_in[9];
    const float* ln2b = (const float*)d_in[10];
    const float* m1w  = (const float*)d_in[11];
    const float* m1b  = (const float*)d_in[12];
    const float* m2w  = (const float*)d_in[13];
    const float* m2b  = (const float*)d_in[14];

    char* ws = (char*)d_ws;
    // ws layout, lifetime-aliased. Peak 234,336,256 B.
    u16*   slot1 = (u16*)(ws + 0);            // 70,246,400 B
    u16*   vbuf  = (u16*)(ws + 70246400);     // 70,246,400 B
    u16*   hn    = (u16*)(ws + 140492800);    // 29,360,128 B
    float* Yf    = (float*)(ws + 169852928);  // 29,360,128 B (8192*896 fp32)
    u16*   qp    = (u16*)(ws + 199213056);    // 17,561,600 B
    u16*   ao    = (u16*)(ws + 216774656);    // 17,561,600 B
    u16*   sskip = slot1;
    u16*   qfull = slot1;
    u16*   kbuf  = slot1;
    u16*   m1    = slot1;
    u16*   hn2   = hn;
    float* outf  = (float*)d_out;

    // 1. hn = LN1(x)
    ln_kernel<448><<<8192, 256, 0, stream>>>(x, ln1g, ln1b, hn, 32768);
    // 2. sskip = hn @ skip_w + skip_b
    gemm_bf16<GA_NONE, EPI_STORE><<<dim3(512, 14), 256, 0, stream>>>(
        hn, sw, 896, sb, sskip, nullptr, nullptr, 32768, 896, 448);
    // 3. y = maxpool2x2(sskip)
    maxpool_skip<<<28672, 256, 0, stream>>>(sskip, Yf, 8192 * 896);
    // 4. qfull = window_gather(hn) @ Wq + bq
    gemm_bf16<GA_WIN, EPI_STORE><<<dim3(613, 14), 256, 0, stream>>>(
        hn, qkvw + 0, 2688, qkvb + 0, qfull, nullptr, nullptr, 39200, 896, 448);
    // 5. qp = maxpool2x2(qfull)
    qpool<<<34300, 256, 0, stream>>>(qfull, qp, 200 * 49 * 896);
    // 6. kbuf = window_gather(hn) @ Wk + bk
    gemm_bf16<GA_WIN, EPI_STORE><<<dim3(613, 14), 256, 0, stream>>>(
        hn, qkvw + 896, 2688, qkvb + 896, kbuf, nullptr, nullptr, 39200, 896, 448);
    // 7. vbuf = window_gather(hn) @ Wv + bv
    gemm_bf16<GA_WIN, EPI_STORE><<<dim3(613, 14), 256, 0, stream>>>(
        hn, qkvw + 1792, 2688, qkvb + 1792, vbuf, nullptr, nullptr, 39200, 896, 448);
    // 8. attention (MFMA)
    attn_mfma<<<3200, 256, 0, stream>>>(qp, kbuf, vbuf, ao);
    // 9. y += window_scatter(ao @ proj_w + proj_b)
    gemm_bf16<GA_NONE, EPI_PROJ><<<dim3(154, 14), 256, 0, stream>>>(
        ao, pw, 896, pb, nullptr, Yf, nullptr, 9800, 896, 896);
    // 10. hn2 = LN2(y)
    ln_kernel<896><<<2048, 256, 0, stream>>>(Yf, ln2g, ln2b, hn2, 8192);
    // 11. m1 = gelu(hn2 @ mlp1_w + mlp1_b)
    gemm_bf16<GA_NONE, EPI_GELU><<<dim3(128, 56), 256, 0, stream>>>(
        hn2, m1w, 3584, m1b, m1, nullptr, nullptr, 8192, 3584, 896);
    // 12. out = y + m1 @ mlp2_w + mlp2_b   (fp32 store)
    gemm_bf16<GA_NONE, EPI_OUT><<<dim3(128, 14), 256, 0, stream>>>(
        m1, m2w, 896, m2b, nullptr, Yf, outf, 8192, 896, 3584);
}

// Round 7
// 833.914 us; speedup vs baseline: 2.2421x; 1.8272x over previous
//
#include <hip/hip_runtime.h>
#include <hip/hip_bf16.h>

typedef unsigned short u16;
typedef __bf16 bf16x8 __attribute__((ext_vector_type(8)));
typedef float f32x4 __attribute__((ext_vector_type(4)));

__device__ __forceinline__ float bf2f(u16 u) {
    unsigned v = ((unsigned)u) << 16;
    return __builtin_bit_cast(float, v);
}
__device__ __forceinline__ u16 f2bf(float f) {
    unsigned x = __builtin_bit_cast(unsigned, f);
    unsigned r = x + (0x7fffu + ((x >> 16) & 1u));   // RNE
    return (u16)(r >> 16);
}
__device__ __forceinline__ void gload16(const void* g, void* l) {
    __builtin_amdgcn_global_load_lds(
        (const __attribute__((address_space(1))) void*)g,
        (__attribute__((address_space(3))) void*)l, 16, 0, 0);
}

// ---------------- weight transpose+convert: fp32 [K][N] -> bf16 [N][K] -------
__global__ __launch_bounds__(256) void transpose_w(const float* __restrict__ src,
    u16* __restrict__ dst, int K, int N)
{
    __shared__ u16 T[64][33];
    int k0 = blockIdx.x * 32, n0 = blockIdx.y * 64;
    int t = threadIdx.x;
    int nc = t & 63, krb = (t >> 6) * 8;
#pragma unroll
    for (int j = 0; j < 8; j++) {
        int kr = krb + j;
        T[nc][kr] = f2bf(src[(size_t)(k0 + kr) * N + n0 + nc]);
    }
    __syncthreads();
    int r = t >> 2, c0 = (t & 3) * 8;
    u16 tmp[8];
#pragma unroll
    for (int i = 0; i < 8; i++) tmp[i] = T[r][c0 + i];
    *(uint4*)&dst[(size_t)(n0 + r) * K + k0 + c0] = *(uint4*)tmp;
}

__global__ void zfill(u16* p) { p[threadIdx.x] = 0; }

// ---------------- LayerNorm: one wave per pixel (fp32 in, bf16 out) ----------
template<int C>
__global__ __launch_bounds__(256) void ln_kernel(const float* __restrict__ xf,
    const float* __restrict__ g, const float* __restrict__ b,
    u16* __restrict__ out, int npix)
{
    int wid = threadIdx.x >> 6, lane = threadIdx.x & 63;
    int pix = blockIdx.x * 4 + wid;
    if (pix >= npix) return;
    constexpr int J = C / 64;
    float v[J];
    float s = 0.f, s2 = 0.f;
#pragma unroll
    for (int j = 0; j < J; j++) {
        int c = lane + j * 64;
        float t = xf[(size_t)pix * C + c];
        v[j] = t; s += t; s2 += t * t;
    }
#pragma unroll
    for (int off = 32; off; off >>= 1) {
        s  += __shfl_xor(s,  off, 64);
        s2 += __shfl_xor(s2, off, 64);
    }
    float mean = s / C;
    float var = fmaxf(s2 / C - mean * mean, 0.f);
    float rs = rsqrtf(var + 1e-6f);
#pragma unroll
    for (int j = 0; j < J; j++) {
        int c = lane + j * 64;
        float o = (v[j] - mean) * rs * g[c] + b[c];
        out[(size_t)pix * C + c] = f2bf(o);
    }
}

// ---------------- 128x128 MFMA GEMM, BK=32, global_load_lds staging ----------
// A: bf16 [M][K] (optionally window-gathered rows). BT: bf16 [N][K]
// (pre-transposed weights). bias fp32. All N,K multiples of 128/32.
enum { GA_NONE = 0, GA_WIN = 1 };
enum { EPI_STORE = 0, EPI_GELU = 1, EPI_PROJ = 2, EPI_OUT = 3 };

template<int GATHER, int EPI>
__global__ __launch_bounds__(256, 3) void gemm128(
    const u16* __restrict__ A, const u16* __restrict__ BT,
    const u16* __restrict__ zrow, const float* __restrict__ bias,
    u16* __restrict__ Cb, float* __restrict__ Yf, float* __restrict__ Of,
    int M, int N, int K)
{
    __shared__ __align__(16) u16 As[128 * 32];
    __shared__ __align__(16) u16 Bs[128 * 32];
    __shared__ int rowsrc[128];

    const int tid = threadIdx.x;
    const int bm = blockIdx.x, bn = blockIdx.y;

    if (tid < 128) {
        int gm = bm * 128 + tid;
        int src = -1;
        if (gm < M) {
            if (GATHER == GA_WIN) {
                int w = gm / 196, t = gm % 196;
                int b = w / 25, wh = (w / 5) % 5, ww = w % 5;
                int ty = t / 14, tx = t % 14;
                int gh = wh * 14 + ty, gw = ww * 14 + tx;
                if (gh < 64 && gw < 64) src = (b * 64 + gh) * 64 + gw;
            } else {
                src = gm;
            }
        }
        rowsrc[tid] = src;
    }
    __syncthreads();

    const int wid = tid >> 6, lane = tid & 63;
    const int wm = wid >> 1, wn = wid & 1;
    const int frow = lane & 15, quad = lane >> 4;

    const int srow = tid >> 2, schunk = tid & 3;   // staging: row/4-lane chunk

    f32x4 acc[4][4] = {};

    for (int k0 = 0; k0 < K; k0 += 32) {
#pragma unroll
        for (int p = 0; p < 2; p++) {
            int r = srow + p * 64;
            int src = rowsrc[r];
            const u16* ga = (src >= 0) ? A + (size_t)src * K + k0 + schunk * 8
                                       : zrow + schunk * 8;
            gload16(ga, &As[r * 32 + schunk * 8]);
            const u16* gb = BT + (size_t)(bn * 128 + r) * K + k0 + schunk * 8;
            gload16(gb, &Bs[r * 32 + schunk * 8]);
        }
        __syncthreads();

        bf16x8 af[4], bf[4];
#pragma unroll
        for (int mi = 0; mi < 4; mi++)
            af[mi] = *(const bf16x8*)&As[(wm * 64 + mi * 16 + frow) * 32 + quad * 8];
#pragma unroll
        for (int ni = 0; ni < 4; ni++)
            bf[ni] = *(const bf16x8*)&Bs[(wn * 64 + ni * 16 + frow) * 32 + quad * 8];
#pragma unroll
        for (int mi = 0; mi < 4; mi++)
#pragma unroll
            for (int ni = 0; ni < 4; ni++)
                acc[mi][ni] = __builtin_amdgcn_mfma_f32_16x16x32_bf16(
                    af[mi], bf[ni], acc[mi][ni], 0, 0, 0);
        __syncthreads();
    }

    // epilogue: D lane layout col = lane&15, row = quad*4 + i
#pragma unroll
    for (int mi = 0; mi < 4; mi++)
#pragma unroll
    for (int ni = 0; ni < 4; ni++)
#pragma unroll
    for (int i = 0; i < 4; i++) {
        int gm = bm * 128 + wm * 64 + mi * 16 + quad * 4 + i;
        int gn = bn * 128 + wn * 64 + ni * 16 + frow;
        if (gm >= M) continue;
        float val = acc[mi][ni][i] + bias[gn];
        if (EPI == EPI_STORE) {
            Cb[(size_t)gm * N + gn] = f2bf(val);
        } else if (EPI == EPI_GELU) {
            float ge = 0.5f * val * (1.0f + erff(val * 0.70710678118654752f));
            Cb[(size_t)gm * N + gn] = f2bf(ge);
        } else if (EPI == EPI_PROJ) {
            int w = gm / 49, q = gm % 49;
            int b = w / 25, wh = (w / 5) % 5, ww = w % 5;
            int qy = q / 7, qx = q % 7;
            int oy = wh * 7 + qy, ox = ww * 7 + qx;
            if (oy < 32 && ox < 32) {
                size_t pix = (size_t)((b * 32 + oy) * 32 + ox);
                Yf[pix * 896 + gn] += val;   // y = shortcut + xo
            }
        } else { // EPI_OUT: final output FP32
            Of[(size_t)gm * 896 + gn] = val + Yf[(size_t)gm * 896 + gn];
        }
    }
}

// ---------------- 2x2 maxpool of skip GEMM output -> y (fp32) ----------------
__global__ __launch_bounds__(256) void maxpool_skip(const u16* __restrict__ s,
                                                    float* __restrict__ y, int total)
{
    int id = blockIdx.x * 256 + threadIdx.x;
    if (id >= total) return;
    int c = id % 896, p = id / 896;
    int b = p >> 10, rem = p & 1023, oy = rem >> 5, ox = rem & 31;
    size_t base = ((size_t)((b * 64 + 2 * oy) * 64 + 2 * ox)) * 896 + c;
    float m = bf2f(s[base]);
    m = fmaxf(m, bf2f(s[base + 896]));
    m = fmaxf(m, bf2f(s[base + 64 * 896]));
    m = fmaxf(m, bf2f(s[base + 64 * 896 + 896]));
    y[id] = m;
}

// ---------------- 2x2 maxpool of qfull (39200x896) -> qp (9800x896) ----------
__global__ __launch_bounds__(256) void qpool(const u16* __restrict__ qf,
                                             u16* __restrict__ qp, int total)
{
    int id = blockIdx.x * 256 + threadIdx.x;
    if (id >= total) return;
    int c = id % 896; int rq = id / 896;
    int q = rq % 49, w = rq / 49;
    int qy = q / 7, qx = q % 7;
    int t0 = (2 * qy) * 14 + 2 * qx;
    size_t base = (size_t)(w * 196 + t0) * 896 + c;
    float m = bf2f(qf[base]);
    m = fmaxf(m, bf2f(qf[base + 896]));
    m = fmaxf(m, bf2f(qf[base + 14 * 896]));
    m = fmaxf(m, bf2f(qf[base + 15 * 896]));
    qp[id] = f2bf(m);
}

// ---------------- MFMA attention: one block per (window, head) ---------------
__global__ __launch_bounds__(256) void attn_mfma(const u16* __restrict__ qp,
    const u16* __restrict__ kbuf, const u16* __restrict__ vbuf,
    u16* __restrict__ ao)
{
    __shared__ __align__(16) u16 Ps[64][232];
    __shared__ __align__(16) u16 KV[208 * 72];

    const float SCALE = 0.13363062095621219f;   // 56^-0.5
    const int w = blockIdx.x >> 4, h = blockIdx.x & 15;
    const int tid = threadIdx.x;
    const int wid = tid >> 6, lane = tid & 63;
    const int n16 = lane & 15, quad = lane >> 4;

    for (int idx = tid; idx < 64 * 232 / 8; idx += 256)
        *(uint4*)&Ps[0][idx * 8] = make_uint4(0u, 0u, 0u, 0u);
    for (int idx = tid; idx < 208 * 9; idx += 256) {
        int n = idx / 9, kc = (idx % 9) * 8;
        uint4 val = make_uint4(0u, 0u, 0u, 0u);
        if (n < 196 && kc < 56)
            val = *(const uint4*)(kbuf + (size_t)(w * 196 + n) * 896 + h * 56 + kc);
        *(uint4*)&KV[n * 72 + kc] = val;
    }
    bf16x8 qf[2];
    {
        int m = 16 * wid + n16;
        int row = w * 49 + (m < 49 ? m : 48);
        const u16* src = qp + (size_t)row * 896 + h * 56;
#pragma unroll
        for (int ks = 0; ks < 2; ks++) {
            int kk = ks * 32 + quad * 8;
            uint4 v = make_uint4(0u, 0u, 0u, 0u);
            if (kk < 56) v = *(const uint4*)(src + kk);
            qf[ks] = __builtin_bit_cast(bf16x8, v);
        }
    }
    __syncthreads();

    f32x4 S[13] = {};
#pragma unroll
    for (int nt = 0; nt < 13; nt++) {
#pragma unroll
        for (int ks = 0; ks < 2; ks++) {
            bf16x8 bf = *(const bf16x8*)&KV[(nt * 16 + n16) * 72 + ks * 32 + quad * 8];
            S[nt] = __builtin_amdgcn_mfma_f32_16x16x32_bf16(qf[ks], bf, S[nt], 0, 0, 0);
        }
    }
#pragma unroll
    for (int i = 0; i < 4; i++) {
        float mx = -3.0e38f;
#pragma unroll
        for (int nt = 0; nt < 13; nt++) {
            float v = S[nt][i] * SCALE;
            S[nt][i] = v;
            if (nt < 12 || n16 < 4) mx = fmaxf(mx, v);
        }
        mx = fmaxf(mx, __shfl_xor(mx, 1, 64));
        mx = fmaxf(mx, __shfl_xor(mx, 2, 64));
        mx = fmaxf(mx, __shfl_xor(mx, 4, 64));
        mx = fmaxf(mx, __shfl_xor(mx, 8, 64));
        float sm = 0.f;
#pragma unroll
        for (int nt = 0; nt < 13; nt++) {
            float e = (nt < 12 || n16 < 4) ? __expf(S[nt][i] - mx) : 0.f;
            S[nt][i] = e;
            sm += e;
        }
        sm += __shfl_xor(sm, 1, 64);
        sm += __shfl_xor(sm, 2, 64);
        sm += __shfl_xor(sm, 4, 64);
        sm += __shfl_xor(sm, 8, 64);
        float inv = 1.f / sm;
#pragma unroll
        for (int nt = 0; nt < 13; nt++) S[nt][i] *= inv;
    }
    __syncthreads();

#pragma unroll
    for (int nt = 0; nt < 13; nt++)
#pragma unroll
        for (int i = 0; i < 4; i++)
            Ps[16 * wid + 4 * quad + i][16 * nt + n16] = f2bf(S[nt][i]);

    u16 (*Vs)[232] = reinterpret_cast<u16(*)[232]>(KV);
    for (int idx = tid; idx < 196 * 56; idx += 256) {
        int j = idx / 56, d = idx % 56;
        Vs[d][j] = vbuf[(size_t)(w * 196 + j) * 896 + h * 56 + d];
    }
    for (int idx = tid; idx < 64 * 14; idx += 256) {
        int d = idx / 14, c = idx % 14;
        *(unsigned*)&Vs[d][196 + 2 * c] = 0u;
    }
    __syncthreads();

    f32x4 O[4] = {};
#pragma unroll
    for (int ks = 0; ks < 7; ks++) {
        bf16x8 a = *(const bf16x8*)&Ps[16 * wid + n16][ks * 32 + quad * 8];
#pragma unroll
        for (int nt = 0; nt < 4; nt++) {
            bf16x8 b = *(const bf16x8*)&Vs[16 * nt + n16][ks * 32 + quad * 8];
            O[nt] = __builtin_amdgcn_mfma_f32_16x16x32_bf16(a, b, O[nt], 0, 0, 0);
        }
    }
#pragma unroll
    for (int nt = 0; nt < 4; nt++)
#pragma unroll
        for (int i = 0; i < 4; i++) {
            int m = 16 * wid + 4 * quad + i;
            int d = 16 * nt + n16;
            if (m < 49 && d < 56)
                ao[(size_t)(w * 49 + m) * 896 + h * 56 + d] = f2bf(O[nt][i]);
        }
}

extern "C" void kernel_launch(void* const* d_in, const int* in_sizes, int n_in,
                              void* d_out, int out_size, void* d_ws, size_t ws_size,
                              hipStream_t stream)
{
    const float* x    = (const float*)d_in[0];
    const float* ln1g = (const float*)d_in[1];
    const float* ln1b = (const float*)d_in[2];
    const float* qkvw = (const float*)d_in[3];
    const float* qkvb = (const float*)d_in[4];
    const float* pw   = (const float*)d_in[5];
    const float* pb   = (const float*)d_in[6];
    const float* sw   = (const float*)d_in[7];
    const float* sb   = (const float*)d_in[8];
    const float* ln2g = (const float*)d_in[9];
    const float* ln2b = (const float*)d_in[10];
    const float* m1w  = (const float*)d_in[11];
    const float* m1b  = (const float*)d_in[12];
    const float* m2w  = (const float*)d_in[13];
    const float* m2b  = (const float*)d_in[14];

    char* ws = (char*)d_ws;
    // ws layout, lifetime-aliased. Peak 239,153,408 B.
    u16*   slot1 = (u16*)(ws + 0);            // 70,246,400 B: sskip/qfull/kbuf/m1
    u16*   vbuf  = (u16*)(ws + 70246400);     // 70,246,400 B; after attn: m1wT/m2wT
    u16*   hn    = (u16*)(ws + 140492800);    // 29,360,128 B; later hn2
    float* Yf    = (float*)(ws + 169852928);  // 29,360,128 B (8192*896 fp32)
    u16*   qp    = (u16*)(ws + 199213056);    // 17,561,600 B
    u16*   ao    = (u16*)(ws + 216774656);    // 17,561,600 B
    u16*   swT   = (u16*)(ws + 234336256);    //    802,816 B (896x448)
    u16*   qkvT  = (u16*)(ws + 235139072);    //  2,408,448 B (2688x448)
    u16*   pwT   = (u16*)(ws + 237547520);    //  1,605,632 B (896x896)
    u16*   zrow  = (u16*)(ws + 239153152);    //        256 B zeros
    u16*   sskip = slot1;
    u16*   qfull = slot1;
    u16*   kbuf  = slot1;
    u16*   m1    = slot1;
    u16*   hn2   = hn;
    u16*   m1wT  = vbuf;                      // 6,422,528 B (3584x896)
    u16*   m2wT  = (u16*)(ws + 70246400 + 6422528); // 6,422,528 B (896x3584)
    float* outf  = (float*)d_out;

    // 0. prep: zero row + transpose early weights to bf16 [N][K]
    zfill<<<1, 128, 0, stream>>>(zrow);
    transpose_w<<<dim3(14, 14), 256, 0, stream>>>(sw,   swT,  448, 896);
    transpose_w<<<dim3(14, 42), 256, 0, stream>>>(qkvw, qkvT, 448, 2688);
    transpose_w<<<dim3(28, 14), 256, 0, stream>>>(pw,   pwT,  896, 896);
    // 1. hn = LN1(x)
    ln_kernel<448><<<8192, 256, 0, stream>>>(x, ln1g, ln1b, hn, 32768);
    // 2. sskip = hn @ skip_w + skip_b
    gemm128<GA_NONE, EPI_STORE><<<dim3(256, 7), 256, 0, stream>>>(
        hn, swT, zrow, sb, sskip, nullptr, nullptr, 32768, 896, 448);
    // 3. y = maxpool2x2(sskip)
    maxpool_skip<<<28672, 256, 0, stream>>>(sskip, Yf, 8192 * 896);
    // 4. qfull = window_gather(hn) @ Wq + bq
    gemm128<GA_WIN, EPI_STORE><<<dim3(307, 7), 256, 0, stream>>>(
        hn, qkvT, zrow, qkvb, qfull, nullptr, nullptr, 39200, 896, 448);
    // 5. qp = maxpool2x2(qfull)
    qpool<<<34300, 256, 0, stream>>>(qfull, qp, 200 * 49 * 896);
    // 6. kbuf = window_gather(hn) @ Wk + bk
    gemm128<GA_WIN, EPI_STORE><<<dim3(307, 7), 256, 0, stream>>>(
        hn, qkvT + (size_t)896 * 448, zrow, qkvb + 896, kbuf, nullptr, nullptr,
        39200, 896, 448);
    // 7. vbuf = window_gather(hn) @ Wv + bv
    gemm128<GA_WIN, EPI_STORE><<<dim3(307, 7), 256, 0, stream>>>(
        hn, qkvT + (size_t)1792 * 448, zrow, qkvb + 1792, vbuf, nullptr, nullptr,
        39200, 896, 448);
    // 8. attention (MFMA)
    attn_mfma<<<3200, 256, 0, stream>>>(qp, kbuf, vbuf, ao);
    // 8b. transpose mlp weights into dead vbuf region
    transpose_w<<<dim3(28, 56),  256, 0, stream>>>(m1w, m1wT, 896, 3584);
    transpose_w<<<dim3(112, 14), 256, 0, stream>>>(m2w, m2wT, 3584, 896);
    // 9. y += window_scatter(ao @ proj_w + proj_b)
    gemm128<GA_NONE, EPI_PROJ><<<dim3(77, 7), 256, 0, stream>>>(
        ao, pwT, zrow, pb, nullptr, Yf, nullptr, 9800, 896, 896);
    // 10. hn2 = LN2(y)
    ln_kernel<896><<<2048, 256, 0, stream>>>(Yf, ln2g, ln2b, hn2, 8192);
    // 11. m1 = gelu(hn2 @ mlp1_w + mlp1_b)
    gemm128<GA_NONE, EPI_GELU><<<dim3(64, 28), 256, 0, stream>>>(
        hn2, m1wT, zrow, m1b, m1, nullptr, nullptr, 8192, 3584, 896);
    // 12. out = y + m1 @ mlp2_w + mlp2_b   (fp32 store)
    gemm128<GA_NONE, EPI_OUT><<<dim3(64, 7), 256, 0, stream>>>(
        m1, m2wT, zrow, m2b, nullptr, Yf, outf, 8192, 896, 3584);
}